// Round 1
// baseline (1329.354 us; speedup 1.0000x reference)
//
#include <hip/hip_runtime.h>
#include <hip/hip_bf16.h>
#include <cstdint>

#define DIM_   1024
#define H_     16
#define DH_    64
#define INNER_ 1024
#define B_     2
#define I_     2048
#define J_     2048
#define SCALE_ 0.125f

using bf16x8 = __attribute__((ext_vector_type(8))) short;
using f32x4  = __attribute__((ext_vector_type(4))) float;

__device__ __forceinline__ unsigned short f2bf(float f) {
  unsigned int u = __float_as_uint(f);
  u = (u + 0x7FFFu + ((u >> 16) & 1u)) >> 16;
  return (unsigned short)u;
}
__device__ __forceinline__ float bf2f(unsigned short h) {
  return __uint_as_float(((unsigned int)h) << 16);
}

// ---------------- LayerNorm + cast to bf16 ----------------
// one block (256 thr) per row of DIM_=1024
__global__ __launch_bounds__(256) void ln_cast_kernel(
    const float* __restrict__ in, const float* __restrict__ g,
    const float* __restrict__ bb, unsigned short* __restrict__ out) {
  int row = blockIdx.x;
  int t = threadIdx.x;
  const float4* rp = (const float4*)(in + (size_t)row * DIM_);
  float4 v = rp[t];
  float s  = v.x + v.y + v.z + v.w;
  float ss = v.x * v.x + v.y * v.y + v.z * v.z + v.w * v.w;
  for (int o = 1; o < 64; o <<= 1) {
    s  += __shfl_xor(s, o, 64);
    ss += __shfl_xor(ss, o, 64);
  }
  __shared__ float ls[4], lss[4];
  int wave = t >> 6, lane = t & 63;
  if (lane == 0) { ls[wave] = s; lss[wave] = ss; }
  __syncthreads();
  s  = ls[0] + ls[1] + ls[2] + ls[3];
  ss = lss[0] + lss[1] + lss[2] + lss[3];
  float mu  = s * (1.0f / DIM_);
  float var = ss * (1.0f / DIM_) - mu * mu;
  float rstd = rsqrtf(var + 1e-5f);
  float4 gv = ((const float4*)g)[t];
  float4 bv = ((const float4*)bb)[t];
  ushort4 o4;
  o4.x = f2bf((v.x - mu) * rstd * gv.x + bv.x);
  o4.y = f2bf((v.y - mu) * rstd * gv.y + bv.y);
  o4.z = f2bf((v.z - mu) * rstd * gv.z + bv.z);
  o4.w = f2bf((v.w - mu) * rstd * gv.w + bv.w);
  ((ushort4*)(out + (size_t)row * DIM_))[t] = o4;
}

// ---------------- transpose + cast f32 -> bf16 ----------------
// out[z][c][r] = (bf16) in[z][r][c]; grid (C/32, R/32, Z), block (32,8)
__global__ __launch_bounds__(256) void transpose_cast_f32(
    const float* __restrict__ in, unsigned short* __restrict__ out, int R, int C) {
  __shared__ float tile[32][33];
  int z = blockIdx.z;
  const float* ip = in + (size_t)z * R * C;
  unsigned short* op = out + (size_t)z * R * C;
  int c0 = blockIdx.x * 32, r0 = blockIdx.y * 32;
  int tx = threadIdx.x, ty = threadIdx.y;
  for (int k = 0; k < 4; k++)
    tile[ty * 4 + k][tx] = ip[(size_t)(r0 + ty * 4 + k) * C + c0 + tx];
  __syncthreads();
  for (int k = 0; k < 4; k++)
    op[(size_t)(c0 + ty * 4 + k) * R + r0 + tx] = f2bf(tile[tx][ty * 4 + k]);
}

// ---------------- transpose bf16 -> bf16 ----------------
__global__ __launch_bounds__(256) void transpose_bf16(
    const unsigned short* __restrict__ in, unsigned short* __restrict__ out, int R, int C) {
  __shared__ unsigned short tile[32][33];
  int z = blockIdx.z;
  const unsigned short* ip = in + (size_t)z * R * C;
  unsigned short* op = out + (size_t)z * R * C;
  int c0 = blockIdx.x * 32, r0 = blockIdx.y * 32;
  int tx = threadIdx.x, ty = threadIdx.y;
  for (int k = 0; k < 4; k++)
    tile[ty * 4 + k][tx] = ip[(size_t)(r0 + ty * 4 + k) * C + c0 + tx];
  __syncthreads();
  for (int k = 0; k < 4; k++)
    op[(size_t)(c0 + ty * 4 + k) * R + r0 + tx] = tile[tx][ty * 4 + k];
}

// ---------------- bf16 GEMM: C[M,N] = A[M,K] @ Bt[N,K]^T (+bias) ----------------
// grid (N/128, M/128), block 256 (4 waves), tile 128x128, BK=32
#define LDP 40
__global__ __launch_bounds__(256) void gemm_bt(
    const unsigned short* __restrict__ A, const unsigned short* __restrict__ Bt,
    const float* __restrict__ bias, void* __restrict__ Cout,
    int M, int N, int K, int c_f32) {
  __shared__ unsigned short As[128 * LDP];
  __shared__ unsigned short Bs[128 * LDP];
  int t = threadIdx.x;
  int lane = t & 63, wave = t >> 6;
  int m0 = blockIdx.y * 128, n0 = blockIdx.x * 128;
  int wm = (wave >> 1) * 64, wn = (wave & 1) * 64;
  int l15 = lane & 15, lk = lane >> 4;
  int lrow = t >> 2, lc8 = (t & 3) * 8;
  f32x4 acc[4][4] = {};

  for (int k0 = 0; k0 < K; k0 += 32) {
    *(bf16x8*)&As[lrow * LDP + lc8]        = *(const bf16x8*)&A[(size_t)(m0 + lrow) * K + k0 + lc8];
    *(bf16x8*)&As[(lrow + 64) * LDP + lc8] = *(const bf16x8*)&A[(size_t)(m0 + lrow + 64) * K + k0 + lc8];
    *(bf16x8*)&Bs[lrow * LDP + lc8]        = *(const bf16x8*)&Bt[(size_t)(n0 + lrow) * K + k0 + lc8];
    *(bf16x8*)&Bs[(lrow + 64) * LDP + lc8] = *(const bf16x8*)&Bt[(size_t)(n0 + lrow + 64) * K + k0 + lc8];
    __syncthreads();
    bf16x8 af[4], bfr[4];
#pragma unroll
    for (int mi = 0; mi < 4; mi++) af[mi]  = *(const bf16x8*)&As[(wm + mi * 16 + l15) * LDP + lk * 8];
#pragma unroll
    for (int ni = 0; ni < 4; ni++) bfr[ni] = *(const bf16x8*)&Bs[(wn + ni * 16 + l15) * LDP + lk * 8];
#pragma unroll
    for (int mi = 0; mi < 4; mi++)
#pragma unroll
      for (int ni = 0; ni < 4; ni++)
        acc[mi][ni] = __builtin_amdgcn_mfma_f32_16x16x32_bf16(af[mi], bfr[ni], acc[mi][ni], 0, 0, 0);
    __syncthreads();
  }
#pragma unroll
  for (int mi = 0; mi < 4; mi++)
#pragma unroll
    for (int ni = 0; ni < 4; ni++) {
      int col = n0 + wn + ni * 16 + l15;
      float bsv = bias ? bias[col] : 0.0f;
#pragma unroll
      for (int r = 0; r < 4; r++) {
        int row = m0 + wm + mi * 16 + lk * 4 + r;
        float val = acc[mi][ni][r] + bsv;
        if (c_f32) ((float*)Cout)[(size_t)row * N + col] = val;
        else ((unsigned short*)Cout)[(size_t)row * N + col] = f2bf(val);
      }
    }
}

// ---------------- stats: rsum[b,h,i] = sum_j exp(SCALE * dot(Q[b,i,h*64:],K[b,j,h*64:])) ----------------
// grid (NQ/32, H, B), block 256 (4 waves); each wave owns a 16-wide j sub-column
__global__ __launch_bounds__(256) void stats_kernel(
    const unsigned short* __restrict__ Q, const unsigned short* __restrict__ Kc,
    float* __restrict__ rsum, int NQ, int NK) {
  int b = blockIdx.z, h = blockIdx.y, i0 = blockIdx.x * 32;
  int t = threadIdx.x, lane = t & 63, wave = t >> 6;
  int l15 = lane & 15, lk = lane >> 4;
  const size_t qbase = ((size_t)b * NQ + i0) * INNER_ + h * DH_;
  bf16x8 af[2][2];
#pragma unroll
  for (int mi = 0; mi < 2; mi++)
#pragma unroll
    for (int ks = 0; ks < 2; ks++)
      af[mi][ks] = *(const bf16x8*)&Q[qbase + (size_t)(mi * 16 + l15) * INNER_ + ks * 32 + lk * 8];
  float racc[2][4] = {};
  for (int j0 = wave * 16; j0 < NK; j0 += 64) {
    const size_t kbase = ((size_t)b * NK + j0 + l15) * INNER_ + h * DH_ + lk * 8;
    bf16x8 b0 = *(const bf16x8*)&Kc[kbase];
    bf16x8 b1 = *(const bf16x8*)&Kc[kbase + 32];
#pragma unroll
    for (int mi = 0; mi < 2; mi++) {
      f32x4 acc = {};
      acc = __builtin_amdgcn_mfma_f32_16x16x32_bf16(af[mi][0], b0, acc, 0, 0, 0);
      acc = __builtin_amdgcn_mfma_f32_16x16x32_bf16(af[mi][1], b1, acc, 0, 0, 0);
#pragma unroll
      for (int r = 0; r < 4; r++) racc[mi][r] += __expf(acc[r] * SCALE_);
    }
  }
#pragma unroll
  for (int o = 1; o < 16; o <<= 1)
#pragma unroll
    for (int mi = 0; mi < 2; mi++)
#pragma unroll
      for (int r = 0; r < 4; r++) racc[mi][r] += __shfl_xor(racc[mi][r], o, 64);
  __shared__ float part[4][32];
  if (l15 == 0)
#pragma unroll
    for (int mi = 0; mi < 2; mi++)
#pragma unroll
      for (int r = 0; r < 4; r++) part[wave][mi * 16 + lk * 4 + r] = racc[mi][r];
  __syncthreads();
  if (t < 32)
    rsum[((size_t)b * H_ + h) * NQ + i0 + t] = part[0][t] + part[1][t] + part[2][t] + part[3][t];
}

// ---------------- fused attention output ----------------
// Oh[b, i, g*64+d] = sum_j ( sum_h thw[g,h]*exp(SCALE*Q_i.K_j)/rsum[b,h,i] ) * Vt[b, g*64+d, j]
// grid (NQ/16, B), block 256 (4 waves). Wave w: sim for j-sub w*16..w*16+15 (all heads),
// then PV for heads g in [4w, 4w+4).
#define MJ 80
#define QLD 1032
__global__ __launch_bounds__(256) void attn_out_kernel(
    const unsigned short* __restrict__ Q, const unsigned short* __restrict__ Kc,
    const unsigned short* __restrict__ Vt, const float* __restrict__ rsum,
    const float* __restrict__ thw, unsigned short* __restrict__ Oh, int NQ, int NK) {
  __shared__ unsigned short Qs[16 * QLD];   // Q tile, pre-scaled by SCALE_
  __shared__ unsigned short Ms[16 * 16 * MJ]; // mixed probs, A-operand layout
  __shared__ float thwT[256];               // thwT[h*16+g] = thw[g*16+h]
  __shared__ float rinvS[256];              // rinvS[h*16+il] = 1/rsum[b,h,i0+il]
  int b = blockIdx.y, i0 = blockIdx.x * 16;
  int t = threadIdx.x, lane = t & 63, wave = t >> 6;
  int l15 = lane & 15, lk = lane >> 4;

  {
    int row = t >> 4, c0 = (t & 15) * 64;
    const unsigned short* qp = Q + ((size_t)b * NQ + i0 + row) * INNER_ + c0;
    unsigned short* qd = &Qs[row * QLD + c0];
#pragma unroll
    for (int c = 0; c < 64; c += 8) {
      bf16x8 vv = *(const bf16x8*)(qp + c);
      bf16x8 ov;
#pragma unroll
      for (int e = 0; e < 8; e++) ov[e] = (short)f2bf(bf2f((unsigned short)vv[e]) * SCALE_);
      *(bf16x8*)(qd + c) = ov;
    }
  }
  thwT[t]  = thw[(t & 15) * H_ + (t >> 4)];
  rinvS[t] = 1.0f / rsum[((size_t)b * H_ + (t >> 4)) * NQ + i0 + (t & 15)];
  __syncthreads();

  f32x4 acc[16] = {};  // [gi*4+nt]

  for (int j0 = 0; j0 < NK; j0 += 64) {
    float Mreg[16][4] = {};
    int jw = j0 + wave * 16;
#pragma unroll 4
    for (int h = 0; h < H_; h++) {
      bf16x8 a0 = *(const bf16x8*)&Qs[l15 * QLD + h * 64 + lk * 8];
      bf16x8 a1 = *(const bf16x8*)&Qs[l15 * QLD + h * 64 + 32 + lk * 8];
      const size_t kb = ((size_t)b * NK + jw + l15) * INNER_ + h * DH_ + lk * 8;
      bf16x8 b0 = *(const bf16x8*)&Kc[kb];
      bf16x8 b1 = *(const bf16x8*)&Kc[kb + 32];
      f32x4 s = {};
      s = __builtin_amdgcn_mfma_f32_16x16x32_bf16(a0, b0, s, 0, 0, 0);
      s = __builtin_amdgcn_mfma_f32_16x16x32_bf16(a1, b1, s, 0, 0, 0);
      f32x4 ri = *(const f32x4*)&rinvS[h * 16 + lk * 4];
      float eh[4];
#pragma unroll
      for (int r = 0; r < 4; r++) eh[r] = __expf(s[r]) * ri[r];
#pragma unroll
      for (int g = 0; g < 16; g += 4) {
        f32x4 tw = *(const f32x4*)&thwT[h * 16 + g];
#pragma unroll
        for (int gg = 0; gg < 4; gg++)
#pragma unroll
          for (int r = 0; r < 4; r++) Mreg[g + gg][r] += tw[gg] * eh[r];
      }
    }
    // write mixed probs to LDS (A-operand layout per g: [16 i][MJ j])
#pragma unroll
    for (int g = 0; g < 16; g++)
#pragma unroll
      for (int r = 0; r < 4; r++)
        Ms[(g * 16 + lk * 4 + r) * MJ + wave * 16 + l15] = f2bf(Mreg[g][r]);
    __syncthreads();
    // PV: wave handles g in [4w,4w+4)
#pragma unroll
    for (int gi = 0; gi < 4; gi++) {
      int g = wave * 4 + gi;
      bf16x8 ma0 = *(const bf16x8*)&Ms[(g * 16 + l15) * MJ + lk * 8];
      bf16x8 ma1 = *(const bf16x8*)&Ms[(g * 16 + l15) * MJ + 32 + lk * 8];
#pragma unroll
      for (int nt = 0; nt < 4; nt++) {
        const size_t vb = ((size_t)b * INNER_ + g * 64 + nt * 16 + l15) * NK + j0 + lk * 8;
        bf16x8 v0 = *(const bf16x8*)&Vt[vb];
        bf16x8 v1 = *(const bf16x8*)&Vt[vb + 32];
        acc[gi * 4 + nt] = __builtin_amdgcn_mfma_f32_16x16x32_bf16(ma0, v0, acc[gi * 4 + nt], 0, 0, 0);
        acc[gi * 4 + nt] = __builtin_amdgcn_mfma_f32_16x16x32_bf16(ma1, v1, acc[gi * 4 + nt], 0, 0, 0);
      }
    }
    __syncthreads();
  }
#pragma unroll
  for (int gi = 0; gi < 4; gi++) {
    int g = wave * 4 + gi;
#pragma unroll
    for (int nt = 0; nt < 4; nt++) {
      int col = g * 64 + nt * 16 + l15;
#pragma unroll
      for (int r = 0; r < 4; r++)
        Oh[((size_t)b * NQ + i0 + lk * 4 + r) * INNER_ + col] = f2bf(acc[gi * 4 + nt][r]);
    }
  }
}

// ---------------- launch ----------------
extern "C" void kernel_launch(void* const* d_in, const int* in_sizes, int n_in,
                              void* d_out, int out_size, void* d_ws, size_t ws_size,
                              hipStream_t stream) {
  const float* x      = (const float*)d_in[0];
  const float* ctx    = (const float*)d_in[1];
  const float* ln_g   = (const float*)d_in[2];
  const float* ln_b   = (const float*)d_in[3];
  const float* cln_g  = (const float*)d_in[4];
  const float* cln_b  = (const float*)d_in[5];
  const float* W_qk   = (const float*)d_in[6];
  const float* W_cqk  = (const float*)d_in[7];
  const float* W_v    = (const float*)d_in[8];
  const float* W_cv   = (const float*)d_in[9];
  const float* W_out  = (const float*)d_in[10];
  const float* b_out  = (const float*)d_in[11];
  const float* W_cout = (const float*)d_in[12];
  const float* b_cout = (const float*)d_in[13];
  const float* th_w   = (const float*)d_in[14];
  const float* cth_w  = (const float*)d_in[15];

  char* w = (char*)d_ws;
  const size_t SZ_ROW = (size_t)B_ * I_ * DIM_ * 2;   // 8 MB (bf16 [B,N,1024])
  const size_t SZ_W   = (size_t)DIM_ * INNER_ * 2;    // 2 MB
  unsigned short* xn    = (unsigned short*)w; w += SZ_ROW;
  unsigned short* cn    = (unsigned short*)w; w += SZ_ROW;
  unsigned short* Wqkt  = (unsigned short*)w; w += SZ_W;
  unsigned short* Wcqkt = (unsigned short*)w; w += SZ_W;
  unsigned short* Wvt   = (unsigned short*)w; w += SZ_W;
  unsigned short* Wcvt  = (unsigned short*)w; w += SZ_W;
  unsigned short* Woutt = (unsigned short*)w; w += SZ_W;
  unsigned short* Wcoutt= (unsigned short*)w; w += SZ_W;
  unsigned short* qk    = (unsigned short*)w; w += SZ_ROW;
  unsigned short* ck    = (unsigned short*)w; w += SZ_ROW;
  unsigned short* vv    = (unsigned short*)w; w += SZ_ROW;
  unsigned short* cv    = (unsigned short*)w; w += SZ_ROW;
  unsigned short* vT    = (unsigned short*)w; w += SZ_ROW;
  unsigned short* cvT   = (unsigned short*)w; w += SZ_ROW;
  float* rsum = (float*)w; w += (size_t)B_ * H_ * I_ * 4;
  float* csum = (float*)w; w += (size_t)B_ * H_ * J_ * 4;
  unsigned short* Oh1 = (unsigned short*)w; w += SZ_ROW;
  unsigned short* Oh2 = (unsigned short*)w; w += SZ_ROW;

  dim3 tb(32, 8);
  ln_cast_kernel<<<B_ * I_, 256, 0, stream>>>(x, ln_g, ln_b, xn);
  ln_cast_kernel<<<B_ * J_, 256, 0, stream>>>(ctx, cln_g, cln_b, cn);

  transpose_cast_f32<<<dim3(32, 32, 1), tb, 0, stream>>>(W_qk,   Wqkt,  DIM_, INNER_);
  transpose_cast_f32<<<dim3(32, 32, 1), tb, 0, stream>>>(W_cqk,  Wcqkt, DIM_, INNER_);
  transpose_cast_f32<<<dim3(32, 32, 1), tb, 0, stream>>>(W_v,    Wvt,   DIM_, INNER_);
  transpose_cast_f32<<<dim3(32, 32, 1), tb, 0, stream>>>(W_cv,   Wcvt,  DIM_, INNER_);
  transpose_cast_f32<<<dim3(32, 32, 1), tb, 0, stream>>>(W_out,  Woutt, INNER_, DIM_);
  transpose_cast_f32<<<dim3(32, 32, 1), tb, 0, stream>>>(W_cout, Wcoutt,INNER_, DIM_);

  gemm_bt<<<dim3(INNER_ / 128, (B_ * I_) / 128), 256, 0, stream>>>(xn, Wqkt,  nullptr, qk, B_ * I_, INNER_, DIM_, 0);
  gemm_bt<<<dim3(INNER_ / 128, (B_ * J_) / 128), 256, 0, stream>>>(cn, Wcqkt, nullptr, ck, B_ * J_, INNER_, DIM_, 0);
  gemm_bt<<<dim3(INNER_ / 128, (B_ * I_) / 128), 256, 0, stream>>>(xn, Wvt,   nullptr, vv, B_ * I_, INNER_, DIM_, 0);
  gemm_bt<<<dim3(INNER_ / 128, (B_ * J_) / 128), 256, 0, stream>>>(cn, Wcvt,  nullptr, cv, B_ * J_, INNER_, DIM_, 0);

  transpose_bf16<<<dim3(INNER_ / 32, I_ / 32, B_), tb, 0, stream>>>(vv, vT, I_, INNER_);
  transpose_bf16<<<dim3(INNER_ / 32, J_ / 32, B_), tb, 0, stream>>>(cv, cvT, J_, INNER_);

  stats_kernel<<<dim3(I_ / 32, H_, B_), 256, 0, stream>>>(qk, ck, rsum, I_, J_);
  stats_kernel<<<dim3(J_ / 32, H_, B_), 256, 0, stream>>>(ck, qk, csum, J_, I_);

  attn_out_kernel<<<dim3(I_ / 16, B_), 256, 0, stream>>>(qk, ck, cvT, rsum, th_w,  Oh1, I_, J_);
  attn_out_kernel<<<dim3(J_ / 16, B_), 256, 0, stream>>>(ck, qk, vT,  csum, cth_w, Oh2, J_, I_);

  gemm_bt<<<dim3(DIM_ / 128, (B_ * I_) / 128), 256, 0, stream>>>(Oh1, Woutt, b_out, (float*)d_out, B_ * I_, DIM_, INNER_, 1);
  gemm_bt<<<dim3(DIM_ / 128, (B_ * J_) / 128), 256, 0, stream>>>(Oh2, Wcoutt, b_cout, ((float*)d_out) + (size_t)B_ * I_ * DIM_, B_ * J_, DIM_, INNER_, 1);
}

// Round 2
// 1187.892 us; speedup vs baseline: 1.1191x; 1.1191x over previous
//
#include <hip/hip_runtime.h>
#include <hip/hip_bf16.h>
#include <cstdint>

#define DIM_   1024
#define H_     16
#define DH_    64
#define INNER_ 1024
#define B_     2
#define I_     2048
#define J_     2048
#define SCALE_ 0.125f

using bf16x8 = __attribute__((ext_vector_type(8))) short;
using f32x4  = __attribute__((ext_vector_type(4))) float;

__device__ __forceinline__ unsigned short f2bf(float f) {
  unsigned int u = __float_as_uint(f);
  u = (u + 0x7FFFu + ((u >> 16) & 1u)) >> 16;
  return (unsigned short)u;
}
__device__ __forceinline__ float bf2f(unsigned short h) {
  return __uint_as_float(((unsigned int)h) << 16);
}

// ---------------- LayerNorm + cast to bf16 ----------------
__global__ __launch_bounds__(256) void ln_cast_kernel(
    const float* __restrict__ in, const float* __restrict__ g,
    const float* __restrict__ bb, unsigned short* __restrict__ out) {
  int row = blockIdx.x;
  int t = threadIdx.x;
  const float4* rp = (const float4*)(in + (size_t)row * DIM_);
  float4 v = rp[t];
  float s  = v.x + v.y + v.z + v.w;
  float ss = v.x * v.x + v.y * v.y + v.z * v.z + v.w * v.w;
  for (int o = 1; o < 64; o <<= 1) {
    s  += __shfl_xor(s, o, 64);
    ss += __shfl_xor(ss, o, 64);
  }
  __shared__ float ls[4], lss[4];
  int wave = t >> 6, lane = t & 63;
  if (lane == 0) { ls[wave] = s; lss[wave] = ss; }
  __syncthreads();
  s  = ls[0] + ls[1] + ls[2] + ls[3];
  ss = lss[0] + lss[1] + lss[2] + lss[3];
  float mu  = s * (1.0f / DIM_);
  float var = ss * (1.0f / DIM_) - mu * mu;
  float rstd = rsqrtf(var + 1e-5f);
  float4 gv = ((const float4*)g)[t];
  float4 bv = ((const float4*)bb)[t];
  ushort4 o4;
  o4.x = f2bf((v.x - mu) * rstd * gv.x + bv.x);
  o4.y = f2bf((v.y - mu) * rstd * gv.y + bv.y);
  o4.z = f2bf((v.z - mu) * rstd * gv.z + bv.z);
  o4.w = f2bf((v.w - mu) * rstd * gv.w + bv.w);
  ((ushort4*)(out + (size_t)row * DIM_))[t] = o4;
}

// ---------------- transpose + cast f32 -> bf16 ----------------
__global__ __launch_bounds__(256) void transpose_cast_f32(
    const float* __restrict__ in, unsigned short* __restrict__ out, int R, int C) {
  __shared__ float tile[32][33];
  int z = blockIdx.z;
  const float* ip = in + (size_t)z * R * C;
  unsigned short* op = out + (size_t)z * R * C;
  int c0 = blockIdx.x * 32, r0 = blockIdx.y * 32;
  int tx = threadIdx.x, ty = threadIdx.y;
  for (int k = 0; k < 4; k++)
    tile[ty * 4 + k][tx] = ip[(size_t)(r0 + ty * 4 + k) * C + c0 + tx];
  __syncthreads();
  for (int k = 0; k < 4; k++)
    op[(size_t)(c0 + ty * 4 + k) * R + r0 + tx] = f2bf(tile[tx][ty * 4 + k]);
}

// ---------------- transpose bf16 -> bf16 ----------------
__global__ __launch_bounds__(256) void transpose_bf16(
    const unsigned short* __restrict__ in, unsigned short* __restrict__ out, int R, int C) {
  __shared__ unsigned short tile[32][33];
  int z = blockIdx.z;
  const unsigned short* ip = in + (size_t)z * R * C;
  unsigned short* op = out + (size_t)z * R * C;
  int c0 = blockIdx.x * 32, r0 = blockIdx.y * 32;
  int tx = threadIdx.x, ty = threadIdx.y;
  for (int k = 0; k < 4; k++)
    tile[ty * 4 + k][tx] = ip[(size_t)(r0 + ty * 4 + k) * C + c0 + tx];
  __syncthreads();
  for (int k = 0; k < 4; k++)
    op[(size_t)(c0 + ty * 4 + k) * R + r0 + tx] = tile[tx][ty * 4 + k];
}

// ---------------- bf16 GEMM: C[M,N] = A[M,K] @ Bt[N,K]^T (+bias) ----------------
#define LDP 40
__global__ __launch_bounds__(256) void gemm_bt(
    const unsigned short* __restrict__ A, const unsigned short* __restrict__ Bt,
    const float* __restrict__ bias, void* __restrict__ Cout,
    int M, int N, int K, int c_f32) {
  __shared__ unsigned short As[128 * LDP];
  __shared__ unsigned short Bs[128 * LDP];
  int t = threadIdx.x;
  int lane = t & 63, wave = t >> 6;
  int m0 = blockIdx.y * 128, n0 = blockIdx.x * 128;
  int wm = (wave >> 1) * 64, wn = (wave & 1) * 64;
  int l15 = lane & 15, lk = lane >> 4;
  int lrow = t >> 2, lc8 = (t & 3) * 8;
  f32x4 acc[4][4] = {};

  for (int k0 = 0; k0 < K; k0 += 32) {
    *(bf16x8*)&As[lrow * LDP + lc8]        = *(const bf16x8*)&A[(size_t)(m0 + lrow) * K + k0 + lc8];
    *(bf16x8*)&As[(lrow + 64) * LDP + lc8] = *(const bf16x8*)&A[(size_t)(m0 + lrow + 64) * K + k0 + lc8];
    *(bf16x8*)&Bs[lrow * LDP + lc8]        = *(const bf16x8*)&Bt[(size_t)(n0 + lrow) * K + k0 + lc8];
    *(bf16x8*)&Bs[(lrow + 64) * LDP + lc8] = *(const bf16x8*)&Bt[(size_t)(n0 + lrow + 64) * K + k0 + lc8];
    __syncthreads();
    bf16x8 af[4], bfr[4];
#pragma unroll
    for (int mi = 0; mi < 4; mi++) af[mi]  = *(const bf16x8*)&As[(wm + mi * 16 + l15) * LDP + lk * 8];
#pragma unroll
    for (int ni = 0; ni < 4; ni++) bfr[ni] = *(const bf16x8*)&Bs[(wn + ni * 16 + l15) * LDP + lk * 8];
#pragma unroll
    for (int mi = 0; mi < 4; mi++)
#pragma unroll
      for (int ni = 0; ni < 4; ni++)
        acc[mi][ni] = __builtin_amdgcn_mfma_f32_16x16x32_bf16(af[mi], bfr[ni], acc[mi][ni], 0, 0, 0);
    __syncthreads();
  }
#pragma unroll
  for (int mi = 0; mi < 4; mi++)
#pragma unroll
    for (int ni = 0; ni < 4; ni++) {
      int col = n0 + wn + ni * 16 + l15;
      float bsv = bias ? bias[col] : 0.0f;
#pragma unroll
      for (int r = 0; r < 4; r++) {
        int row = m0 + wm + mi * 16 + lk * 4 + r;
        float val = acc[mi][ni][r] + bsv;
        if (c_f32) ((float*)Cout)[(size_t)row * N + col] = val;
        else ((unsigned short*)Cout)[(size_t)row * N + col] = f2bf(val);
      }
    }
}

// ---------------- stats: rsum[b,h,i] = sum_j exp(SCALE * dot(...)) ----------------
__global__ __launch_bounds__(256) void stats_kernel(
    const unsigned short* __restrict__ Q, const unsigned short* __restrict__ Kc,
    float* __restrict__ rsum, int NQ, int NK) {
  int b = blockIdx.z, h = blockIdx.y, i0 = blockIdx.x * 32;
  int t = threadIdx.x, lane = t & 63, wave = t >> 6;
  int l15 = lane & 15, lk = lane >> 4;
  const size_t qbase = ((size_t)b * NQ + i0) * INNER_ + h * DH_;
  bf16x8 af[2][2];
#pragma unroll
  for (int mi = 0; mi < 2; mi++)
#pragma unroll
    for (int ks = 0; ks < 2; ks++)
      af[mi][ks] = *(const bf16x8*)&Q[qbase + (size_t)(mi * 16 + l15) * INNER_ + ks * 32 + lk * 8];
  float racc[2][4] = {};
  for (int j0 = wave * 16; j0 < NK; j0 += 64) {
    const size_t kbase = ((size_t)b * NK + j0 + l15) * INNER_ + h * DH_ + lk * 8;
    bf16x8 b0 = *(const bf16x8*)&Kc[kbase];
    bf16x8 b1 = *(const bf16x8*)&Kc[kbase + 32];
#pragma unroll
    for (int mi = 0; mi < 2; mi++) {
      f32x4 acc = {};
      acc = __builtin_amdgcn_mfma_f32_16x16x32_bf16(af[mi][0], b0, acc, 0, 0, 0);
      acc = __builtin_amdgcn_mfma_f32_16x16x32_bf16(af[mi][1], b1, acc, 0, 0, 0);
#pragma unroll
      for (int r = 0; r < 4; r++) racc[mi][r] += __expf(acc[r] * SCALE_);
    }
  }
#pragma unroll
  for (int o = 1; o < 16; o <<= 1)
#pragma unroll
    for (int mi = 0; mi < 2; mi++)
#pragma unroll
      for (int r = 0; r < 4; r++) racc[mi][r] += __shfl_xor(racc[mi][r], o, 64);
  __shared__ float part[4][32];
  if (l15 == 0)
#pragma unroll
    for (int mi = 0; mi < 2; mi++)
#pragma unroll
      for (int r = 0; r < 4; r++) part[wave][mi * 16 + lk * 4 + r] = racc[mi][r];
  __syncthreads();
  if (t < 32)
    rsum[((size_t)b * H_ + h) * NQ + i0 + t] = part[0][t] + part[1][t] + part[2][t] + part[3][t];
}

// ---------------- fused attention output (j-chunked, f32 partial out) ----------------
// grid (NQ/16, JSPLIT, B), block 256 (4 waves). Wave w: sim+mix for j-sub w*16,
// PV for heads g in [4w,4w+4). Partial O (f32) per j-chunk; reduced later.
#define MJ 72
__global__ __launch_bounds__(256) void attn_out_kernel(
    const unsigned short* __restrict__ Q, const unsigned short* __restrict__ Kc,
    const unsigned short* __restrict__ Vt, const float* __restrict__ rsum,
    const float* __restrict__ thw,
    float* __restrict__ p0, float* __restrict__ p1,
    float* __restrict__ p2, float* __restrict__ p3,
    int NQ, int NK, int CHUNK) {
  __shared__ unsigned short Ms[16 * 16 * MJ]; // mixed probs, A-operand layout
  __shared__ float thwT[256];                 // thwT[h*16+g] = thw[g*16+h]
  __shared__ float rinvS[256];                // rinvS[h*16+il] = 1/rsum
  int jc = blockIdx.y, b = blockIdx.z;
  int i0 = blockIdx.x * 16;
  float* __restrict__ Op = (jc == 0) ? p0 : (jc == 1) ? p1 : (jc == 2) ? p2 : p3;
  int t = threadIdx.x, lane = t & 63, wave = t >> 6;
  int l15 = lane & 15, lk = lane >> 4;

  thwT[t]  = thw[(t & 15) * H_ + (t >> 4)];
  rinvS[t] = 1.0f / rsum[((size_t)b * H_ + (t >> 4)) * NQ + i0 + (t & 15)];
  __syncthreads();

  const unsigned short* qrow = Q + ((size_t)b * NQ + i0 + l15) * INNER_;
  f32x4 acc[16] = {};  // [gi*4+nt]
  const int jbeg = jc * CHUNK;

  for (int js = 0; js < CHUNK; js += 64) {
    int j0 = jbeg + js;
    int jw = j0 + wave * 16;
    const unsigned short* krow = Kc + ((size_t)b * NK + jw + l15) * INNER_;
    int qo = 0;
    asm volatile("" : "+v"(qo));  // defeat LICM: Q frags re-read (L1 hit) each step
    float Mreg[16][4] = {};
#pragma unroll 4
    for (int h = 0; h < H_; h++) {
      bf16x8 a0 = *(const bf16x8*)&qrow[qo + h * 64 + lk * 8];
      bf16x8 a1 = *(const bf16x8*)&qrow[qo + h * 64 + 32 + lk * 8];
      bf16x8 b0 = *(const bf16x8*)&krow[h * 64 + lk * 8];
      bf16x8 b1 = *(const bf16x8*)&krow[h * 64 + 32 + lk * 8];
      f32x4 s = {};
      s = __builtin_amdgcn_mfma_f32_16x16x32_bf16(a0, b0, s, 0, 0, 0);
      s = __builtin_amdgcn_mfma_f32_16x16x32_bf16(a1, b1, s, 0, 0, 0);
      f32x4 ri = *(const f32x4*)&rinvS[h * 16 + lk * 4];
      float eh[4];
#pragma unroll
      for (int r = 0; r < 4; r++) eh[r] = __expf(s[r] * SCALE_) * ri[r];
#pragma unroll
      for (int g = 0; g < 16; g += 4) {
        f32x4 tw = *(const f32x4*)&thwT[h * 16 + g];
#pragma unroll
        for (int gg = 0; gg < 4; gg++)
#pragma unroll
          for (int r = 0; r < 4; r++) Mreg[g + gg][r] += tw[gg] * eh[r];
      }
    }
#pragma unroll
    for (int g = 0; g < 16; g++)
#pragma unroll
      for (int r = 0; r < 4; r++)
        Ms[(g * 16 + lk * 4 + r) * MJ + wave * 16 + l15] = f2bf(Mreg[g][r]);
    __syncthreads();
#pragma unroll
    for (int gi = 0; gi < 4; gi++) {
      int g = wave * 4 + gi;
      bf16x8 ma0 = *(const bf16x8*)&Ms[(g * 16 + l15) * MJ + lk * 8];
      bf16x8 ma1 = *(const bf16x8*)&Ms[(g * 16 + l15) * MJ + 32 + lk * 8];
#pragma unroll
      for (int nt = 0; nt < 4; nt++) {
        const size_t vb = ((size_t)b * INNER_ + g * 64 + nt * 16 + l15) * NK + j0 + lk * 8;
        bf16x8 v0 = *(const bf16x8*)&Vt[vb];
        bf16x8 v1 = *(const bf16x8*)&Vt[vb + 32];
        acc[gi * 4 + nt] = __builtin_amdgcn_mfma_f32_16x16x32_bf16(ma0, v0, acc[gi * 4 + nt], 0, 0, 0);
        acc[gi * 4 + nt] = __builtin_amdgcn_mfma_f32_16x16x32_bf16(ma1, v1, acc[gi * 4 + nt], 0, 0, 0);
      }
    }
    __syncthreads();
  }
#pragma unroll
  for (int gi = 0; gi < 4; gi++) {
    int g = wave * 4 + gi;
#pragma unroll
    for (int nt = 0; nt < 4; nt++) {
      int col = g * 64 + nt * 16 + l15;
#pragma unroll
      for (int r = 0; r < 4; r++)
        Op[((size_t)b * NQ + i0 + lk * 4 + r) * INNER_ + col] = acc[gi * 4 + nt][r];
    }
  }
}

// ---------------- reduce partials + cast to bf16 ----------------
__global__ __launch_bounds__(256) void reduce_cast_kernel(
    const float* __restrict__ p0, const float* __restrict__ p1,
    const float* __restrict__ p2, const float* __restrict__ p3,
    unsigned short* __restrict__ out, int n4) {
  int idx = blockIdx.x * 256 + threadIdx.x;
  if (idx >= n4) return;
  float4 v = ((const float4*)p0)[idx];
  float4 w = ((const float4*)p1)[idx];
  v.x += w.x; v.y += w.y; v.z += w.z; v.w += w.w;
  if (p2) {
    float4 a = ((const float4*)p2)[idx];
    float4 c = ((const float4*)p3)[idx];
    v.x += a.x + c.x; v.y += a.y + c.y; v.z += a.z + c.z; v.w += a.w + c.w;
  }
  ushort4 o;
  o.x = f2bf(v.x); o.y = f2bf(v.y); o.z = f2bf(v.z); o.w = f2bf(v.w);
  ((ushort4*)out)[idx] = o;
}

// ---------------- launch ----------------
extern "C" void kernel_launch(void* const* d_in, const int* in_sizes, int n_in,
                              void* d_out, int out_size, void* d_ws, size_t ws_size,
                              hipStream_t stream) {
  const float* x      = (const float*)d_in[0];
  const float* ctx    = (const float*)d_in[1];
  const float* ln_g   = (const float*)d_in[2];
  const float* ln_b   = (const float*)d_in[3];
  const float* cln_g  = (const float*)d_in[4];
  const float* cln_b  = (const float*)d_in[5];
  const float* W_qk   = (const float*)d_in[6];
  const float* W_cqk  = (const float*)d_in[7];
  const float* W_v    = (const float*)d_in[8];
  const float* W_cv   = (const float*)d_in[9];
  const float* W_out  = (const float*)d_in[10];
  const float* b_out  = (const float*)d_in[11];
  const float* W_cout = (const float*)d_in[12];
  const float* b_cout = (const float*)d_in[13];
  const float* th_w   = (const float*)d_in[14];
  const float* cth_w  = (const float*)d_in[15];

  char* w = (char*)d_ws;
  const size_t SZ_ROW = (size_t)B_ * I_ * DIM_ * 2;   // 8 MB (bf16 [B,N,1024])
  const size_t SZ_W   = (size_t)DIM_ * INNER_ * 2;    // 2 MB
  unsigned short* xn    = (unsigned short*)w; w += SZ_ROW;
  unsigned short* cn    = (unsigned short*)w; w += SZ_ROW;
  unsigned short* Wqkt  = (unsigned short*)w; w += SZ_W;
  unsigned short* Wcqkt = (unsigned short*)w; w += SZ_W;
  unsigned short* Wvt   = (unsigned short*)w; w += SZ_W;
  unsigned short* Wcvt  = (unsigned short*)w; w += SZ_W;
  unsigned short* Woutt = (unsigned short*)w; w += SZ_W;
  unsigned short* Wcoutt= (unsigned short*)w; w += SZ_W;
  unsigned short* qk    = (unsigned short*)w; w += SZ_ROW;
  unsigned short* ck    = (unsigned short*)w; w += SZ_ROW;
  unsigned short* vv    = (unsigned short*)w; w += SZ_ROW;
  unsigned short* cv    = (unsigned short*)w; w += SZ_ROW;
  unsigned short* vT    = (unsigned short*)w; w += SZ_ROW;
  unsigned short* cvT   = (unsigned short*)w; w += SZ_ROW;
  float* rsum = (float*)w; w += (size_t)B_ * H_ * I_ * 4;
  float* csum = (float*)w; w += (size_t)B_ * H_ * J_ * 4;
  unsigned short* Oh1 = (unsigned short*)w; w += SZ_ROW;
  unsigned short* Oh2 = (unsigned short*)w; w += SZ_ROW;

  // f32 partial buffers (B*2048*1024 f32 = 16.78 MB each).
  // p0 overlays xn+cn (dead after input GEMMs), p1 overlays vv+cv (dead after
  // transposes). p2/p3 are fresh if ws allows; else fall back to JSPLIT=2.
  const size_t PART = (size_t)B_ * I_ * INNER_ * 4;
  size_t used = (size_t)(w - (char*)d_ws);
  float* pr0 = (float*)xn;
  float* pr1 = (float*)vv;
  float* pr2 = nullptr;
  float* pr3 = nullptr;
  int jsplit = 2;
  if (ws_size >= used + 2 * PART) {
    pr2 = (float*)w;
    pr3 = (float*)(w + PART);
    jsplit = 4;
  }
  const int CHUNK = J_ / jsplit;

  dim3 tb(32, 8);
  ln_cast_kernel<<<B_ * I_, 256, 0, stream>>>(x, ln_g, ln_b, xn);
  ln_cast_kernel<<<B_ * J_, 256, 0, stream>>>(ctx, cln_g, cln_b, cn);

  transpose_cast_f32<<<dim3(32, 32, 1), tb, 0, stream>>>(W_qk,   Wqkt,  DIM_, INNER_);
  transpose_cast_f32<<<dim3(32, 32, 1), tb, 0, stream>>>(W_cqk,  Wcqkt, DIM_, INNER_);
  transpose_cast_f32<<<dim3(32, 32, 1), tb, 0, stream>>>(W_v,    Wvt,   DIM_, INNER_);
  transpose_cast_f32<<<dim3(32, 32, 1), tb, 0, stream>>>(W_cv,   Wcvt,  DIM_, INNER_);
  transpose_cast_f32<<<dim3(32, 32, 1), tb, 0, stream>>>(W_out,  Woutt, INNER_, DIM_);
  transpose_cast_f32<<<dim3(32, 32, 1), tb, 0, stream>>>(W_cout, Wcoutt,INNER_, DIM_);

  gemm_bt<<<dim3(INNER_ / 128, (B_ * I_) / 128), 256, 0, stream>>>(xn, Wqkt,  nullptr, qk, B_ * I_, INNER_, DIM_, 0);
  gemm_bt<<<dim3(INNER_ / 128, (B_ * J_) / 128), 256, 0, stream>>>(cn, Wcqkt, nullptr, ck, B_ * J_, INNER_, DIM_, 0);
  gemm_bt<<<dim3(INNER_ / 128, (B_ * I_) / 128), 256, 0, stream>>>(xn, Wvt,   nullptr, vv, B_ * I_, INNER_, DIM_, 0);
  gemm_bt<<<dim3(INNER_ / 128, (B_ * J_) / 128), 256, 0, stream>>>(cn, Wcvt,  nullptr, cv, B_ * J_, INNER_, DIM_, 0);

  transpose_bf16<<<dim3(INNER_ / 32, I_ / 32, B_), tb, 0, stream>>>(vv, vT, I_, INNER_);
  transpose_bf16<<<dim3(INNER_ / 32, J_ / 32, B_), tb, 0, stream>>>(cv, cvT, J_, INNER_);

  stats_kernel<<<dim3(I_ / 32, H_, B_), 256, 0, stream>>>(qk, ck, rsum, I_, J_);
  stats_kernel<<<dim3(J_ / 32, H_, B_), 256, 0, stream>>>(ck, qk, csum, J_, I_);

  const int n4 = (B_ * I_ * INNER_) / 4;
  // direction 1: softmax over j, output rows i
  attn_out_kernel<<<dim3(I_ / 16, jsplit, B_), 256, 0, stream>>>(
      qk, ck, cvT, rsum, th_w, pr0, pr1, pr2, pr3, I_, J_, CHUNK);
  reduce_cast_kernel<<<n4 / 256, 256, 0, stream>>>(pr0, pr1, pr2, pr3, Oh1, n4);
  // direction 2: softmax over i, output rows j (reuses partial buffers)
  attn_out_kernel<<<dim3(J_ / 16, jsplit, B_), 256, 0, stream>>>(
      ck, qk, vT, csum, cth_w, pr0, pr1, pr2, pr3, J_, I_, CHUNK);
  reduce_cast_kernel<<<n4 / 256, 256, 0, stream>>>(pr0, pr1, pr2, pr3, Oh2, n4);

  gemm_bt<<<dim3(DIM_ / 128, (B_ * I_) / 128), 256, 0, stream>>>(Oh1, Woutt, b_out, (float*)d_out, B_ * I_, DIM_, INNER_, 1);
  gemm_bt<<<dim3(DIM_ / 128, (B_ * J_) / 128), 256, 0, stream>>>(Oh2, Wcoutt, b_cout, ((float*)d_out) + (size_t)B_ * I_ * DIM_, B_ * J_, DIM_, INNER_, 1);
}